// Round 1
// baseline (549.115 us; speedup 1.0000x reference)
//
#include <hip/hip_runtime.h>
#include <hip/hip_bf16.h>

// ---------------- problem constants ----------------
static constexpr float EPS_   = 1e-6f;
static constexpr float SCALE_ = 0.07216878364870323f;  // 192^-0.5
static constexpr float LOG2_1E4_OVER_32 = 13.287712379549449f / 32.0f;

// ---------------- workspace layout (float offsets) ----------------
static constexpr long OFF_QLAT = 0;                        // 64*1536
static constexpr long OFF_Q    = OFF_QLAT + 64L * 1536;    // 64*6144
static constexpr long OFF_KVR  = OFF_Q    + 64L * 6144;    // 64*192
static constexpr long OFF_O    = OFF_KVR  + 64L * 192;     // 64*6144
static constexpr long OFF_LAT  = OFF_O    + 64L * 6144;    // 64*4096
static constexpr long ZERO_F   = OFF_LAT  + 64L * 4096;    // zero [0, ZERO_F)
static constexpr long OFF_SELM = ZERO_F;                   // 2048
static constexpr long OFF_SELI = OFF_SELM + 2048;          // 2048
static constexpr long OFF_SELT = OFF_SELI + 2048;          // 2048 (uint bits)
static constexpr long OFF_LOG  = OFF_SELT + 2048;          // 64*32*4096

// ---------------- types / helpers ----------------
typedef __attribute__((ext_vector_type(8))) short bf16x8;
typedef __attribute__((ext_vector_type(4))) float f32x4;

__device__ __forceinline__ unsigned fkey(float f) {
    unsigned u = __float_as_uint(f);
    return (u & 0x80000000u) ? ~u : (u | 0x80000000u);
}
__device__ __forceinline__ float kval(unsigned k) {
    unsigned u = (k & 0x80000000u) ? (k ^ 0x80000000u) : ~k;
    return __uint_as_float(u);
}
__device__ __forceinline__ unsigned short f2bf(float f) {
    __hip_bfloat16 h = __float2bfloat16(f);
    return *reinterpret_cast<unsigned short*>(&h);
}
__device__ __forceinline__ bf16x8 pack8(float4 v0, float4 v1) {
    bf16x8 s;
    s[0] = (short)f2bf(v0.x); s[1] = (short)f2bf(v0.y);
    s[2] = (short)f2bf(v0.z); s[3] = (short)f2bf(v0.w);
    s[4] = (short)f2bf(v1.x); s[5] = (short)f2bf(v1.y);
    s[6] = (short)f2bf(v1.z); s[7] = (short)f2bf(v1.w);
    return s;
}

// Wave-aggregated LDS histogram add: one atomic per distinct bin per wave.
// Cost scales with #distinct bins in the wave — cheapest exactly when the
// plain-atomic path serializes worst (all lanes in one bin).
__device__ __forceinline__ void hist_add_agg(int* hist, unsigned bin, bool pred) {
    const int lane = (int)(threadIdx.x & 63);
    while (__any(pred)) {
        unsigned long long act = __ballot(pred);
        int leader = __ffsll((unsigned long long)act) - 1;
        unsigned lbin = (unsigned)__shfl((int)bin, leader, 64);
        bool mine = pred && (bin == lbin);
        unsigned long long grp = __ballot(mine);
        if (lane == leader) atomicAdd(&hist[lbin], (int)__popcll(grp));
        if (mine) pred = false;
    }
}

// ============================================================
// MFMA skinny GEMM: C[64 x M] += X[64 x K] * W[M x K]^T (bf16 in, f32 acc)
// grid: (M/TN, K/kslice, batch); 256 threads (4 waves); atomicAdd epilogue.
// LDS [row][k] bf16, BK=64, b128-unit XOR swizzle (u ^= row&7).
// ============================================================
template <int TN>
__global__ __launch_bounds__(256) void gemm_mfma(
    const float* __restrict__ Xb, const float* __restrict__ Wb,
    float* __restrict__ Cb, int K, int ldX, int ldC, int kslice,
    long sXz, long sWz, long sCz)
{
    const float* X = Xb + (long)blockIdx.z * sXz;
    const float* W = Wb + (long)blockIdx.z * sWz;
    float*       C = Cb + (long)blockIdx.z * sCz;
    const int col0 = blockIdx.x * TN;
    const int k0   = blockIdx.y * kslice;

    __shared__ unsigned short Xs[64 * 64];
    __shared__ unsigned short Ws[TN * 64];

    const int t = threadIdx.x;
    const int w = t >> 6, lane = t & 63;
    const int m16 = lane & 15, qd = lane >> 4;
    constexpr int NT = TN / 64;          // n-tiles per wave (2 or 1)

    f32x4 acc[4][NT];
#pragma unroll
    for (int mt = 0; mt < 4; ++mt)
#pragma unroll
        for (int nt = 0; nt < NT; ++nt) acc[mt][nt] = (f32x4){0.f, 0.f, 0.f, 0.f};

    for (int kt = k0; kt < k0 + kslice; kt += 64) {
        // stage X: 64 rows x 8 units
#pragma unroll
        for (int i = 0; i < 2; ++i) {
            int idx = t + i * 256;
            int r = idx >> 3, u = idx & 7;
            const float* p = X + (long)r * ldX + kt + u * 8;
            float4 v0 = *(const float4*)p, v1 = *(const float4*)(p + 4);
            *(bf16x8*)(Xs + r * 64 + (u ^ (r & 7)) * 8) = pack8(v0, v1);
        }
        // stage W: TN rows x 8 units
#pragma unroll
        for (int i = 0; i < TN / 32; ++i) {
            int idx = t + i * 256;
            int r = idx >> 3, u = idx & 7;
            const float* p = W + (long)(col0 + r) * K + kt + u * 8;
            float4 v0 = *(const float4*)p, v1 = *(const float4*)(p + 4);
            *(bf16x8*)(Ws + r * 64 + (u ^ (r & 7)) * 8) = pack8(v0, v1);
        }
        __syncthreads();
#pragma unroll
        for (int ks = 0; ks < 2; ++ks) {
            int u = ks * 4 + qd;
            bf16x8 a[4], b[NT];
#pragma unroll
            for (int mt = 0; mt < 4; ++mt) {
                int row = mt * 16 + m16;
                a[mt] = *(const bf16x8*)(Xs + row * 64 + (u ^ (row & 7)) * 8);
            }
#pragma unroll
            for (int nt = 0; nt < NT; ++nt) {
                int row = (w * NT + nt) * 16 + m16;
                b[nt] = *(const bf16x8*)(Ws + row * 64 + (u ^ (row & 7)) * 8);
            }
#pragma unroll
            for (int mt = 0; mt < 4; ++mt)
#pragma unroll
                for (int nt = 0; nt < NT; ++nt)
                    acc[mt][nt] = __builtin_amdgcn_mfma_f32_16x16x32_bf16(a[mt], b[nt], acc[mt][nt], 0, 0, 0);
        }
        __syncthreads();
    }
#pragma unroll
    for (int mt = 0; mt < 4; ++mt)
#pragma unroll
        for (int nt = 0; nt < NT; ++nt) {
            int col = col0 + (w * NT + nt) * 16 + m16;
#pragma unroll
            for (int r = 0; r < 4; ++r) {
                int row = mt * 16 + qd * 4 + r;
                atomicAdd(&C[(long)row * ldC + col], acc[mt][nt][r]);
            }
        }
}

// ============================================================
// RMS norm over rows (in-place)
// ============================================================
__global__ __launch_bounds__(256) void rms_rows(
    float* __restrict__ x, const float* __restrict__ w, int len)
{
    __shared__ float fred[4];
    float* row = x + (long)blockIdx.x * len;
    int t = threadIdx.x;
    float ss = 0.f;
    for (int l = t; l < len; l += 256) { float v = row[l]; ss += v * v; }
#pragma unroll
    for (int off = 32; off; off >>= 1) ss += __shfl_xor(ss, off, 64);
    if ((t & 63) == 0) fred[t >> 6] = ss;
    __syncthreads();
    ss = fred[0] + fred[1] + fred[2] + fred[3];
    float scale = rsqrtf(ss / (float)len + EPS_);
    for (int l = t; l < len; l += 256) row[l] = row[l] * scale * w[l];
}

// ============================================================
// RoPE on q
// ============================================================
__global__ __launch_bounds__(256) void rope_q(float* __restrict__ q,
                                              const int* __restrict__ cl)
{
    int n = blockIdx.x;
    float pos = (float)(cl[n] - 1);
    int t = threadIdx.x;
#pragma unroll
    for (int i = 0; i < 4; ++i) {
        int f = t + i * 256;
        int h = f >> 5, r = f & 31;
        float inv = exp2f(-(float)r * LOG2_1E4_OVER_32);
        float ang = pos * inv;
        float sn, cs;
        sincosf(ang, &sn, &cs);
        float* p = q + (long)n * 6144 + h * 192 + 128 + 2 * r;
        float x0 = p[0], x1 = p[1];
        p[0] = x0 * cs - x1 * sn;
        p[1] = x0 * sn + x1 * cs;
    }
}

// ============================================================
// KV post: RMS + RoPE + scatter into cache
// ============================================================
__global__ __launch_bounds__(256) void kv_post(
    const float* __restrict__ kvr, const float* __restrict__ wnorm,
    const int* __restrict__ cl, const int* __restrict__ smap,
    float* __restrict__ kvcache)
{
    __shared__ float s[192];
    __shared__ float fred[4];
    int n = blockIdx.x, t = threadIdx.x;
    float v = (t < 192) ? kvr[(long)n * 192 + t] : 0.f;
    float ss = v * v;
#pragma unroll
    for (int off = 32; off; off >>= 1) ss += __shfl_xor(ss, off, 64);
    if ((t & 63) == 0) fred[t >> 6] = ss;
    __syncthreads();
    ss = fred[0] + fred[1] + fred[2] + fred[3];
    float scale = rsqrtf(ss / 192.f + EPS_);
    if (t < 192) s[t] = v * scale * wnorm[t];
    __syncthreads();
    if (t < 32) {
        float pos = (float)(cl[n] - 1);
        float inv = exp2f(-(float)t * LOG2_1E4_OVER_32);
        float ang = pos * inv;
        float sn, cs;
        sincosf(ang, &sn, &cs);
        float x0 = s[128 + 2 * t], x1 = s[128 + 2 * t + 1];
        s[128 + 2 * t]     = x0 * cs - x1 * sn;
        s[128 + 2 * t + 1] = x0 * sn + x1 * cs;
    }
    __syncthreads();
    if (t < 192) kvcache[(long)smap[n] * 192 + t] = s[t];
}

// ============================================================
// MFMA attention logits: grid (16 superchunks of 256 l, 64 n), 256 thr.
// q staged ONCE per block; 2 kv chunks of 128 l looped per block.
// ============================================================
__global__ __launch_bounds__(256) void attn_logits_mfma(
    const float* __restrict__ q, const float* __restrict__ kvc,
    const int* __restrict__ bt, const int* __restrict__ cl,
    float* __restrict__ logits)
{
    const int n = blockIdx.y, sbase = blockIdx.x * 256;
    const int ctx = cl[n];
    if (sbase >= ctx) return;

    __shared__ unsigned short qs[32 * 192];    // [h][d]
    __shared__ unsigned short kvs[128 * 192];  // [l][d]
    const int t = threadIdx.x;
    const int w = t >> 6, lane = t & 63;
    const int m16 = lane & 15, qd = lane >> 4;

    // stage q once per block
#pragma unroll
    for (int i = 0; i < 3; ++i) {
        int idx = t + i * 256;
        int h = idx / 24, u = idx - h * 24;
        const float* p = q + (long)n * 6144 + h * 192 + u * 8;
        float4 v0 = *(const float4*)p, v1 = *(const float4*)(p + 4);
        *(bf16x8*)(qs + h * 192 + (u ^ (h & 7)) * 8) = pack8(v0, v1);
    }

    for (int c = 0; c < 2; ++c) {
        const int base = sbase + c * 128;
        if (base >= ctx) break;

#pragma unroll
        for (int i = 0; i < 12; ++i) {
            int idx = t + i * 256;
            int l = idx / 24, u = idx - l * 24;
            int gl = min(base + l, ctx - 1);
            int slot = bt[n * 64 + (gl >> 6)] * 64 + (gl & 63);
            const float* p = kvc + (long)slot * 192 + u * 8;
            float4 v0 = *(const float4*)p, v1 = *(const float4*)(p + 4);
            *(bf16x8*)(kvs + l * 192 + (u ^ (l & 7)) * 8) = pack8(v0, v1);
        }
        __syncthreads();   // also covers qs staging on first iteration

        f32x4 acc[2][2];
#pragma unroll
        for (int mt = 0; mt < 2; ++mt)
#pragma unroll
            for (int nt = 0; nt < 2; ++nt) acc[mt][nt] = (f32x4){0.f, 0.f, 0.f, 0.f};

#pragma unroll
        for (int ks = 0; ks < 6; ++ks) {
            int u = ks * 4 + qd;
            bf16x8 a[2], b[2];
#pragma unroll
            for (int mt = 0; mt < 2; ++mt) {
                int row = mt * 16 + m16;
                a[mt] = *(const bf16x8*)(qs + row * 192 + (u ^ (row & 7)) * 8);
            }
#pragma unroll
            for (int nt = 0; nt < 2; ++nt) {
                int row = (2 * w + nt) * 16 + m16;
                b[nt] = *(const bf16x8*)(kvs + row * 192 + (u ^ (row & 7)) * 8);
            }
#pragma unroll
            for (int mt = 0; mt < 2; ++mt)
#pragma unroll
                for (int nt = 0; nt < 2; ++nt)
                    acc[mt][nt] = __builtin_amdgcn_mfma_f32_16x16x32_bf16(a[mt], b[nt], acc[mt][nt], 0, 0, 0);
        }
#pragma unroll
        for (int mt = 0; mt < 2; ++mt)
#pragma unroll
            for (int nt = 0; nt < 2; ++nt) {
                int l = base + (2 * w + nt) * 16 + m16;
#pragma unroll
                for (int r = 0; r < 4; ++r) {
                    int h = mt * 16 + qd * 4 + r;
                    logits[((long)(n * 32 + h) << 12) + l] = acc[mt][nt][r] * SCALE_;
                }
            }
        __syncthreads();   // kvs reuse in next chunk
    }
}

// ============================================================
// Exact top-1024 threshold via radix select + softmax stats.
// Round-3 histogram is wave-aggregated (logit exponents concentrate into
// few bins -> plain LDS atomics serialize ~64-way); suffix sum is a shfl
// scan instead of 255 serial LDS reads per thread.
// ============================================================
__global__ __launch_bounds__(256) void select_topk(
    const float* __restrict__ logits, const int* __restrict__ cl,
    const float* __restrict__ sink, float* __restrict__ selm,
    float* __restrict__ seli, unsigned* __restrict__ selt)
{
    int nh = blockIdx.x, n = nh >> 5, h = nh & 31;
    int ctx = cl[n];
    const float* row = logits + ((long)nh << 12);

    __shared__ unsigned keys[4096];
    __shared__ int hist[256];
    __shared__ float fred[4];
    __shared__ int wsumi[4];
    __shared__ unsigned s_pref;
    __shared__ int s_R;

    int t = threadIdx.x;
    int lane = t & 63, wv = t >> 6;
    bool need_radix = (ctx > 1024);

    hist[t] = 0;
    __syncthreads();

    // load + key + max + (fused) round-3 histogram
    float mx = -3.0e38f;
    for (int l0 = 0; l0 < ctx; l0 += 256) {
        int l = l0 + t;
        bool valid = l < ctx;
        unsigned k = 0;
        if (valid) {
            float v = row[l];
            k = fkey(v);
            keys[l] = k;
            mx = fmaxf(mx, v);
        }
        if (need_radix) hist_add_agg(hist, k >> 24, valid);
    }
#pragma unroll
    for (int off = 32; off; off >>= 1) mx = fmaxf(mx, __shfl_xor(mx, off, 64));
    if (lane == 0) fred[wv] = mx;
    __syncthreads();   // also guards hist completion for round 3
    mx = fmaxf(fmaxf(fred[0], fred[1]), fmaxf(fred[2], fred[3]));

    unsigned tau = 0;
    if (need_radix) {
        unsigned pref = 0;
        int R = 1024;
        for (int round = 3; round >= 0; --round) {
            int sh = round * 8;
            if (round < 3) {
                hist[t] = 0;
                __syncthreads();
                for (int l0 = 0; l0 < ctx; l0 += 256) {
                    int l = l0 + t;
                    if (l < ctx) {
                        unsigned k = keys[l];
                        if ((k >> (sh + 8)) == (pref >> (sh + 8)))
                            atomicAdd(&hist[(k >> sh) & 255], 1);
                    }
                }
                __syncthreads();
            }
            // parallel exclusive suffix sum: cum = sum_{b > t} hist[b]
            int hv = hist[t];
            int v = hv;
#pragma unroll
            for (int off = 1; off < 64; off <<= 1) {
                int u2 = __shfl_down(v, off, 64);
                if (lane + off < 64) v += u2;
            }
            if (lane == 0) wsumi[wv] = v;   // wave total
            __syncthreads();
            int above = 0;
#pragma unroll
            for (int w2 = 1; w2 < 4; ++w2)
                if (wv + w2 < 4) above += wsumi[wv + w2];
            int cum = (v - hv) + above;
            if (cum < R && cum + hv >= R) {
                s_pref = pref | ((unsigned)t << sh);
                s_R = R - cum;
            }
            __syncthreads();
            pref = s_pref;
            R = s_R;
            __syncthreads();
        }
        tau = pref;
    }

    float m = fmaxf(mx, sink[h]);
    float part = 0.f;
    for (int l = t; l < ctx; l += 256) {
        unsigned k = keys[l];
        if (k >= tau) part += __expf(kval(k) - m);
    }
#pragma unroll
    for (int off = 32; off; off >>= 1) part += __shfl_xor(part, off, 64);
    __syncthreads();
    if (lane == 0) fred[wv] = part;
    __syncthreads();
    if (t == 0) {
        float denom = fred[0] + fred[1] + fred[2] + fred[3] + __expf(sink[h] - m);
        selm[nh] = m;
        seli[nh] = 1.0f / denom;
        selt[nh] = tau;
    }
}

// ============================================================
// MFMA weighted sum: grid (16 superchunks of 256 l, 64 n), 256 thr.
// 2 l-chunks accumulated in registers per block -> atomic volume halved;
// sel params hoisted out of the chunk loop.
// ============================================================
__global__ __launch_bounds__(256) void attn_wsum_mfma(
    const float* __restrict__ logits, const float* __restrict__ kvc,
    const int* __restrict__ bt, const int* __restrict__ cl,
    const float* __restrict__ selm, const float* __restrict__ seli,
    const unsigned* __restrict__ selt, float* __restrict__ o)
{
    const int n = blockIdx.y, sbase = blockIdx.x * 256;
    const int ctx = cl[n];
    if (sbase >= ctx) return;

    __shared__ unsigned short ps[32 * 128];    // [h][l]
    __shared__ unsigned short kvt[192 * 128];  // [d][l]
    const int t = threadIdx.x;
    const int w = t >> 6, lane = t & 63;
    const int m16 = lane & 15, qd = lane >> 4;

    // per-head softmax params: h fixed per (t,i) -> load once
    float sm[2], sinv[2];
    unsigned stau[2];
#pragma unroll
    for (int i = 0; i < 2; ++i) {
        int nh = n * 32 + ((t + i * 256) >> 4);
        sm[i] = selm[nh];
        sinv[i] = seli[nh];
        stau[i] = selt[nh];
    }

    f32x4 acc[2][3];
#pragma unroll
    for (int mt = 0; mt < 2; ++mt)
#pragma unroll
        for (int nt = 0; nt < 3; ++nt) acc[mt][nt] = (f32x4){0.f, 0.f, 0.f, 0.f};

    for (int c = 0; c < 2; ++c) {
        const int base = sbase + c * 128;
        if (base >= ctx) break;
        const int vcount = min(128, ctx - base);

#pragma unroll
        for (int i = 0; i < 2; ++i) {
            int idx = t + i * 256;
            int hh = idx >> 4, u = idx & 15;
            int nh = n * 32 + hh;
            const float* lp = logits + ((long)nh << 12) + base + u * 8;
            float4 v0 = *(const float4*)lp, v1 = *(const float4*)(lp + 4);
            float vv[8] = {v0.x, v0.y, v0.z, v0.w, v1.x, v1.y, v1.z, v1.w};
            bf16x8 s;
#pragma unroll
            for (int j = 0; j < 8; ++j) {
                int ll = u * 8 + j;
                float p = 0.f;
                if (ll < vcount && fkey(vv[j]) >= stau[i]) p = __expf(vv[j] - sm[i]) * sinv[i];
                s[j] = (short)f2bf(p);
            }
            *(bf16x8*)(ps + hh * 128 + (u ^ (hh & 7)) * 8) = s;
        }
#pragma unroll
        for (int i = 0; i < 24; ++i) {
            int f = t + i * 256;
            int l = f & 127, d4 = f >> 7;
            int gl = min(base + l, ctx - 1);
            int slot = bt[n * 64 + (gl >> 6)] * 64 + (gl & 63);
            float4 v = *(const float4*)(kvc + (long)slot * 192 + d4 * 4);
            float vv[4] = {v.x, v.y, v.z, v.w};
#pragma unroll
            for (int e = 0; e < 4; ++e) {
                int d = d4 * 4 + e;
                int scol = (l & 7) | ((((l >> 3) ^ (d & 7)) & 15) << 3);
                kvt[d * 128 + scol] = f2bf(vv[e]);
            }
        }
        __syncthreads();

#pragma unroll
        for (int ks = 0; ks < 4; ++ks) {
            int u = ks * 4 + qd;
            bf16x8 a[2], b[3];
#pragma unroll
            for (int mt = 0; mt < 2; ++mt) {
                int row = mt * 16 + m16;
                a[mt] = *(const bf16x8*)(ps + row * 128 + (u ^ (row & 7)) * 8);
            }
#pragma unroll
            for (int nt = 0; nt < 3; ++nt) {
                int row = (3 * w + nt) * 16 + m16;
                b[nt] = *(const bf16x8*)(kvt + row * 128 + (u ^ (row & 7)) * 8);
            }
#pragma unroll
            for (int mt = 0; mt < 2; ++mt)
#pragma unroll
                for (int nt = 0; nt < 3; ++nt)
                    acc[mt][nt] = __builtin_amdgcn_mfma_f32_16x16x32_bf16(a[mt], b[nt], acc[mt][nt], 0, 0, 0);
        }
        __syncthreads();   // LDS reuse in next chunk
    }

#pragma unroll
    for (int mt = 0; mt < 2; ++mt)
#pragma unroll
        for (int nt = 0; nt < 3; ++nt) {
            int d = (3 * w + nt) * 16 + m16;
#pragma unroll
            for (int r = 0; r < 4; ++r) {
                int h = mt * 16 + qd * 4 + r;
                atomicAdd(&o[(long)n * 6144 + h * 192 + d], acc[mt][nt][r]);
            }
        }
}

// ============================================================
// launch
// ============================================================
extern "C" void kernel_launch(void* const* d_in, const int* in_sizes, int n_in,
                              void* d_out, int out_size, void* d_ws, size_t ws_size,
                              hipStream_t stream)
{
    const float* x    = (const float*)d_in[0];
    float*       kvc  = (float*)d_in[1];
    const int*   bt   = (const int*)d_in[2];
    const int*   cl   = (const int*)d_in[3];
    const int*   smap = (const int*)d_in[4];
    const float* wqa  = (const float*)d_in[5];
    const float* qnw  = (const float*)d_in[6];
    const float* wqb  = (const float*)d_in[7];
    const float* wkv  = (const float*)d_in[8];
    const float* kvnw = (const float*)d_in[9];
    const float* woa  = (const float*)d_in[10];
    const float* wob  = (const float*)d_in[11];
    const float* sink = (const float*)d_in[12];
    float* ws  = (float*)d_ws;
    float* out = (float*)d_out;

    hipMemsetAsync(ws, 0, (size_t)ZERO_F * sizeof(float), stream);
    hipMemsetAsync(out, 0, (size_t)out_size * sizeof(float), stream);

    // qlat = x @ wq_a^T   (64x1536, K=4096)
    gemm_mfma<128><<<dim3(12, 16, 1), 256, 0, stream>>>(x, wqa, ws + OFF_QLAT,
                                                        4096, 4096, 1536, 256, 0, 0, 0);
    rms_rows<<<64, 256, 0, stream>>>(ws + OFF_QLAT, qnw, 1536);
    // q = qlat @ wq_b^T   (64x6144, K=1536)
    gemm_mfma<128><<<dim3(48, 6, 1), 256, 0, stream>>>(ws + OFF_QLAT, wqb, ws + OFF_Q,
                                                       1536, 1536, 6144, 256, 0, 0, 0);
    rope_q<<<64, 256, 0, stream>>>(ws + OFF_Q, cl);
    // kv = x @ wkv^T   (64x192, K=4096)
    gemm_mfma<64><<<dim3(3, 32, 1), 256, 0, stream>>>(x, wkv, ws + OFF_KVR,
                                                      4096, 4096, 192, 128, 0, 0, 0);
    kv_post<<<64, 256, 0, stream>>>(ws + OFF_KVR, kvnw, cl, smap, kvc);
    // attention (MFMA bf16)
    attn_logits_mfma<<<dim3(16, 64), 256, 0, stream>>>(ws + OFF_Q, kvc, bt, cl,
                                                       ws + OFF_LOG);
    select_topk<<<2048, 256, 0, stream>>>(ws + OFF_LOG, cl, sink,
                                          ws + OFF_SELM, ws + OFF_SELI,
                                          (unsigned*)(ws + OFF_SELT));
    attn_wsum_mfma<<<dim3(16, 64), 256, 0, stream>>>(ws + OFF_LOG, kvc, bt, cl,
                                                     ws + OFF_SELM, ws + OFF_SELI,
                                                     (unsigned*)(ws + OFF_SELT),
                                                     ws + OFF_O);
    // grouped wo_a: 8 batches, 64x512, K=768
    gemm_mfma<128><<<dim3(4, 3, 8), 256, 0, stream>>>(ws + OFF_O, woa, ws + OFF_LAT,
                                                      768, 6144, 4096, 256,
                                                      768, 512L * 768, 512);
    // out = lat @ wo_b^T  (64x4096, K=4096)
    gemm_mfma<128><<<dim3(32, 8, 1), 256, 0, stream>>>(ws + OFF_LAT, wob, out,
                                                       4096, 4096, 4096, 512, 0, 0, 0);
}

// Round 2
// 530.226 us; speedup vs baseline: 1.0356x; 1.0356x over previous
//
#include <hip/hip_runtime.h>
#include <hip/hip_bf16.h>

// ---------------- problem constants ----------------
static constexpr float EPS_   = 1e-6f;
static constexpr float SCALE_ = 0.07216878364870323f;  // 192^-0.5
static constexpr float LOG2_1E4_OVER_32 = 13.287712379549449f / 32.0f;

// ---------------- workspace layout (float offsets) ----------------
// merged [qlat | kvr] buffer: 64 rows x 1728 cols (1536 qlat + 192 kv)
static constexpr long OFF_QK   = 0;                        // 64*1728
static constexpr long OFF_Q    = OFF_QK   + 64L * 1728;    // 64*6144
static constexpr long OFF_O    = OFF_Q    + 64L * 6144;    // 64*6144
static constexpr long OFF_LAT  = OFF_O    + 64L * 6144;    // 64*4096
static constexpr long ZERO_F   = OFF_LAT  + 64L * 4096;    // zero [0, ZERO_F)
static constexpr long OFF_SELM = ZERO_F;                   // 2048
static constexpr long OFF_SELI = OFF_SELM + 2048;          // 2048
static constexpr long OFF_SELT = OFF_SELI + 2048;          // 2048 (uint bits)
static constexpr long OFF_LOG  = OFF_SELT + 2048;          // 64*32*4096

// ---------------- types / helpers ----------------
typedef __attribute__((ext_vector_type(8))) short bf16x8;
typedef __attribute__((ext_vector_type(4))) float f32x4;

__device__ __forceinline__ unsigned fkey(float f) {
    unsigned u = __float_as_uint(f);
    return (u & 0x80000000u) ? ~u : (u | 0x80000000u);
}
__device__ __forceinline__ float kval(unsigned k) {
    unsigned u = (k & 0x80000000u) ? (k ^ 0x80000000u) : ~k;
    return __uint_as_float(u);
}
__device__ __forceinline__ unsigned short f2bf(float f) {
    __hip_bfloat16 h = __float2bfloat16(f);
    return *reinterpret_cast<unsigned short*>(&h);
}
__device__ __forceinline__ bf16x8 pack8(float4 v0, float4 v1) {
    bf16x8 s;
    s[0] = (short)f2bf(v0.x); s[1] = (short)f2bf(v0.y);
    s[2] = (short)f2bf(v0.z); s[3] = (short)f2bf(v0.w);
    s[4] = (short)f2bf(v1.x); s[5] = (short)f2bf(v1.y);
    s[6] = (short)f2bf(v1.z); s[7] = (short)f2bf(v1.w);
    return s;
}

// Wave-aggregated LDS histogram add: one atomic per distinct bin per wave.
__device__ __forceinline__ void hist_add_agg(int* hist, unsigned bin, bool pred) {
    const int lane = (int)(threadIdx.x & 63);
    while (__any(pred)) {
        unsigned long long act = __ballot(pred);
        int leader = __ffsll((unsigned long long)act) - 1;
        unsigned lbin = (unsigned)__shfl((int)bin, leader, 64);
        bool mine = pred && (bin == lbin);
        unsigned long long grp = __ballot(mine);
        if (lane == leader) atomicAdd(&hist[lbin], (int)__popcll(grp));
        if (mine) pred = false;
    }
}

// ============================================================
// MFMA skinny GEMM: C[64 x M] += X[64 x K] * W[M x K]^T (bf16 in, f32 acc)
// grid: (M/TN, K/kslice, batch); 256 threads (4 waves); atomicAdd epilogue.
// Optional: second weight matrix W2 for rows >= split (column-concat GEMM);
// optional zero-job (zbuf/zcount) folded in to save a memset dispatch.
// ============================================================
template <int TN>
__global__ __launch_bounds__(256) void gemm_mfma(
    const float* __restrict__ Xb, const float* __restrict__ Wb,
    float* __restrict__ Cb, int K, int ldX, int ldC, int kslice,
    long sXz, long sWz, long sCz,
    const float* __restrict__ W2, int split,
    float* __restrict__ zbuf, long zcount)
{
    if (zbuf) {  // fold a buffer-zero job in (completes before next kernel)
        int nb = gridDim.x * gridDim.y * gridDim.z;
        int bid = (blockIdx.z * gridDim.y + blockIdx.y) * gridDim.x + blockIdx.x;
        long stride = (long)nb * 256;
        for (long i = (long)bid * 256 + threadIdx.x; i * 4 < zcount; i += stride)
            *(float4*)(zbuf + i * 4) = (float4){0.f, 0.f, 0.f, 0.f};
    }

    const float* X = Xb + (long)blockIdx.z * sXz;
    const float* W = Wb + (long)blockIdx.z * sWz;
    float*       C = Cb + (long)blockIdx.z * sCz;
    const int col0 = blockIdx.x * TN;
    const int k0   = blockIdx.y * kslice;

    __shared__ unsigned short Xs[64 * 64];
    __shared__ unsigned short Ws[TN * 64];

    const int t = threadIdx.x;
    const int w = t >> 6, lane = t & 63;
    const int m16 = lane & 15, qd = lane >> 4;
    constexpr int NT = TN / 64;          // n-tiles per wave (2 or 1)

    f32x4 acc[4][NT];
#pragma unroll
    for (int mt = 0; mt < 4; ++mt)
#pragma unroll
        for (int nt = 0; nt < NT; ++nt) acc[mt][nt] = (f32x4){0.f, 0.f, 0.f, 0.f};

    for (int kt = k0; kt < k0 + kslice; kt += 64) {
        // stage X: 64 rows x 8 units
#pragma unroll
        for (int i = 0; i < 2; ++i) {
            int idx = t + i * 256;
            int r = idx >> 3, u = idx & 7;
            const float* p = X + (long)r * ldX + kt + u * 8;
            float4 v0 = *(const float4*)p, v1 = *(const float4*)(p + 4);
            *(bf16x8*)(Xs + r * 64 + (u ^ (r & 7)) * 8) = pack8(v0, v1);
        }
        // stage W: TN rows x 8 units (row source switches at `split`)
#pragma unroll
        for (int i = 0; i < TN / 32; ++i) {
            int idx = t + i * 256;
            int r = idx >> 3, u = idx & 7;
            int gcol = col0 + r;
            const float* wrow = (gcol < split) ? (W + (long)gcol * K)
                                               : (W2 + (long)(gcol - split) * K);
            const float* p = wrow + kt + u * 8;
            float4 v0 = *(const float4*)p, v1 = *(const float4*)(p + 4);
            *(bf16x8*)(Ws + r * 64 + (u ^ (r & 7)) * 8) = pack8(v0, v1);
        }
        __syncthreads();
#pragma unroll
        for (int ks = 0; ks < 2; ++ks) {
            int u = ks * 4 + qd;
            bf16x8 a[4], b[NT];
#pragma unroll
            for (int mt = 0; mt < 4; ++mt) {
                int row = mt * 16 + m16;
                a[mt] = *(const bf16x8*)(Xs + row * 64 + (u ^ (row & 7)) * 8);
            }
#pragma unroll
            for (int nt = 0; nt < NT; ++nt) {
                int row = (w * NT + nt) * 16 + m16;
                b[nt] = *(const bf16x8*)(Ws + row * 64 + (u ^ (row & 7)) * 8);
            }
#pragma unroll
            for (int mt = 0; mt < 4; ++mt)
#pragma unroll
                for (int nt = 0; nt < NT; ++nt)
                    acc[mt][nt] = __builtin_amdgcn_mfma_f32_16x16x32_bf16(a[mt], b[nt], acc[mt][nt], 0, 0, 0);
        }
        __syncthreads();
    }
#pragma unroll
    for (int mt = 0; mt < 4; ++mt)
#pragma unroll
        for (int nt = 0; nt < NT; ++nt) {
            int col = col0 + (w * NT + nt) * 16 + m16;
#pragma unroll
            for (int r = 0; r < 4; ++r) {
                int row = mt * 16 + qd * 4 + r;
                atomicAdd(&C[(long)row * ldC + col], acc[mt][nt][r]);
            }
        }
}

// ============================================================
// post_a: fused {RMS of qlat row (cols 0..1535)} +
//         {RMS + RoPE + cache-scatter of kv (cols 1536..1727)}
// on the merged [qlat|kvr] buffer (ld 1728). grid = 64 (one per n).
// ============================================================
__global__ __launch_bounds__(256) void post_a(
    float* __restrict__ qk, const float* __restrict__ qnw,
    const float* __restrict__ kvnw, const int* __restrict__ cl,
    const int* __restrict__ smap, float* __restrict__ kvcache)
{
    __shared__ float fred[4];
    __shared__ float s[192];
    int n = blockIdx.x, t = threadIdx.x;
    int lane = t & 63, wv = t >> 6;
    float* row = qk + (long)n * 1728;

    // ---- q-latent RMS over [0,1536) ----
    float ss = 0.f;
    for (int l = t; l < 1536; l += 256) { float v = row[l]; ss += v * v; }
#pragma unroll
    for (int off = 32; off; off >>= 1) ss += __shfl_xor(ss, off, 64);
    if (lane == 0) fred[wv] = ss;
    __syncthreads();
    ss = fred[0] + fred[1] + fred[2] + fred[3];
    float qscale = rsqrtf(ss / 1536.f + EPS_);
    for (int l = t; l < 1536; l += 256) row[l] = row[l] * qscale * qnw[l];

    // ---- kv RMS + RoPE + scatter over [1536,1728) ----
    float v = (t < 192) ? row[1536 + t] : 0.f;
    float s2 = v * v;
#pragma unroll
    for (int off = 32; off; off >>= 1) s2 += __shfl_xor(s2, off, 64);
    __syncthreads();                   // fred reuse
    if (lane == 0) fred[wv] = s2;
    __syncthreads();
    s2 = fred[0] + fred[1] + fred[2] + fred[3];
    float kscale = rsqrtf(s2 / 192.f + EPS_);
    if (t < 192) s[t] = v * kscale * kvnw[t];
    __syncthreads();
    if (t < 32) {
        float pos = (float)(cl[n] - 1);
        float inv = exp2f(-(float)t * LOG2_1E4_OVER_32);
        float ang = pos * inv;
        float sn, cs;
        sincosf(ang, &sn, &cs);
        float x0 = s[128 + 2 * t], x1 = s[128 + 2 * t + 1];
        s[128 + 2 * t]     = x0 * cs - x1 * sn;
        s[128 + 2 * t + 1] = x0 * sn + x1 * cs;
    }
    __syncthreads();
    if (t < 192) kvcache[(long)smap[n] * 192 + t] = s[t];
}

// ============================================================
// MFMA attention logits: grid (16 superchunks of 256 l, 64 n), 256 thr.
// q staged ONCE per block with RoPE applied on the fly (d >= 128 pairs);
// 2 kv chunks of 128 l looped per block.
// ============================================================
__global__ __launch_bounds__(256) void attn_logits_mfma(
    const float* __restrict__ q, const float* __restrict__ kvc,
    const int* __restrict__ bt, const int* __restrict__ cl,
    float* __restrict__ logits)
{
    const int n = blockIdx.y, sbase = blockIdx.x * 256;
    const int ctx = cl[n];
    if (sbase >= ctx) return;
    const float pos = (float)(ctx - 1);

    __shared__ unsigned short qs[32 * 192];    // [h][d]
    __shared__ unsigned short kvs[128 * 192];  // [l][d]
    const int t = threadIdx.x;
    const int w = t >> 6, lane = t & 63;
    const int m16 = lane & 15, qd = lane >> 4;

    // stage q once per block, fusing RoPE on d in [128,192)
#pragma unroll
    for (int i = 0; i < 3; ++i) {
        int idx = t + i * 256;
        int h = idx / 24, u = idx - h * 24;
        const float* p = q + (long)n * 6144 + h * 192 + u * 8;
        float4 v0 = *(const float4*)p, v1 = *(const float4*)(p + 4);
        if (u >= 16) {
            int r0 = 4 * (u - 16);
            float sn, cs, a0, a1;
            sincosf(pos * exp2f(-(float)(r0)     * LOG2_1E4_OVER_32), &sn, &cs);
            a0 = v0.x * cs - v0.y * sn; a1 = v0.x * sn + v0.y * cs; v0.x = a0; v0.y = a1;
            sincosf(pos * exp2f(-(float)(r0 + 1) * LOG2_1E4_OVER_32), &sn, &cs);
            a0 = v0.z * cs - v0.w * sn; a1 = v0.z * sn + v0.w * cs; v0.z = a0; v0.w = a1;
            sincosf(pos * exp2f(-(float)(r0 + 2) * LOG2_1E4_OVER_32), &sn, &cs);
            a0 = v1.x * cs - v1.y * sn; a1 = v1.x * sn + v1.y * cs; v1.x = a0; v1.y = a1;
            sincosf(pos * exp2f(-(float)(r0 + 3) * LOG2_1E4_OVER_32), &sn, &cs);
            a0 = v1.z * cs - v1.w * sn; a1 = v1.z * sn + v1.w * cs; v1.z = a0; v1.w = a1;
        }
        *(bf16x8*)(qs + h * 192 + (u ^ (h & 7)) * 8) = pack8(v0, v1);
    }

    for (int c = 0; c < 2; ++c) {
        const int base = sbase + c * 128;
        if (base >= ctx) break;

#pragma unroll
        for (int i = 0; i < 12; ++i) {
            int idx = t + i * 256;
            int l = idx / 24, u = idx - l * 24;
            int gl = min(base + l, ctx - 1);
            int slot = bt[n * 64 + (gl >> 6)] * 64 + (gl & 63);
            const float* p = kvc + (long)slot * 192 + u * 8;
            float4 v0 = *(const float4*)p, v1 = *(const float4*)(p + 4);
            *(bf16x8*)(kvs + l * 192 + (u ^ (l & 7)) * 8) = pack8(v0, v1);
        }
        __syncthreads();   // also covers qs staging on first iteration

        f32x4 acc[2][2];
#pragma unroll
        for (int mt = 0; mt < 2; ++mt)
#pragma unroll
            for (int nt = 0; nt < 2; ++nt) acc[mt][nt] = (f32x4){0.f, 0.f, 0.f, 0.f};

#pragma unroll
        for (int ks = 0; ks < 6; ++ks) {
            int u = ks * 4 + qd;
            bf16x8 a[2], b[2];
#pragma unroll
            for (int mt = 0; mt < 2; ++mt) {
                int row = mt * 16 + m16;
                a[mt] = *(const bf16x8*)(qs + row * 192 + (u ^ (row & 7)) * 8);
            }
#pragma unroll
            for (int nt = 0; nt < 2; ++nt) {
                int row = (2 * w + nt) * 16 + m16;
                b[nt] = *(const bf16x8*)(kvs + row * 192 + (u ^ (row & 7)) * 8);
            }
#pragma unroll
            for (int mt = 0; mt < 2; ++mt)
#pragma unroll
                for (int nt = 0; nt < 2; ++nt)
                    acc[mt][nt] = __builtin_amdgcn_mfma_f32_16x16x32_bf16(a[mt], b[nt], acc[mt][nt], 0, 0, 0);
        }
#pragma unroll
        for (int mt = 0; mt < 2; ++mt)
#pragma unroll
            for (int nt = 0; nt < 2; ++nt) {
                int l = base + (2 * w + nt) * 16 + m16;
#pragma unroll
                for (int r = 0; r < 4; ++r) {
                    int h = mt * 16 + qd * 4 + r;
                    logits[((long)(n * 32 + h) << 12) + l] = acc[mt][nt][r] * SCALE_;
                }
            }
        __syncthreads();   // kvs reuse in next chunk
    }
}

// ============================================================
// Exact top-1024 threshold via radix select + softmax stats.
// ============================================================
__global__ __launch_bounds__(256) void select_topk(
    const float* __restrict__ logits, const int* __restrict__ cl,
    const float* __restrict__ sink, float* __restrict__ selm,
    float* __restrict__ seli, unsigned* __restrict__ selt)
{
    int nh = blockIdx.x, n = nh >> 5, h = nh & 31;
    int ctx = cl[n];
    const float* row = logits + ((long)nh << 12);

    __shared__ unsigned keys[4096];
    __shared__ int hist[256];
    __shared__ float fred[4];
    __shared__ int wsumi[4];
    __shared__ unsigned s_pref;
    __shared__ int s_R;

    int t = threadIdx.x;
    int lane = t & 63, wv = t >> 6;
    bool need_radix = (ctx > 1024);

    hist[t] = 0;
    __syncthreads();

    // load + key + max + (fused) round-3 histogram
    float mx = -3.0e38f;
    for (int l0 = 0; l0 < ctx; l0 += 256) {
        int l = l0 + t;
        bool valid = l < ctx;
        unsigned k = 0;
        if (valid) {
            float v = row[l];
            k = fkey(v);
            keys[l] = k;
            mx = fmaxf(mx, v);
        }
        if (need_radix) hist_add_agg(hist, k >> 24, valid);
    }
#pragma unroll
    for (int off = 32; off; off >>= 1) mx = fmaxf(mx, __shfl_xor(mx, off, 64));
    if (lane == 0) fred[wv] = mx;
    __syncthreads();   // also guards hist completion for round 3
    mx = fmaxf(fmaxf(fred[0], fred[1]), fmaxf(fred[2], fred[3]));

    unsigned tau = 0;
    if (need_radix) {
        unsigned pref = 0;
        int R = 1024;
        for (int round = 3; round >= 0; --round) {
            int sh = round * 8;
            if (round < 3) {
                hist[t] = 0;
                __syncthreads();
                for (int l0 = 0; l0 < ctx; l0 += 256) {
                    int l = l0 + t;
                    if (l < ctx) {
                        unsigned k = keys[l];
                        if ((k >> (sh + 8)) == (pref >> (sh + 8)))
                            atomicAdd(&hist[(k >> sh) & 255], 1);
                    }
                }
                __syncthreads();
            }
            // parallel exclusive suffix sum: cum = sum_{b > t} hist[b]
            int hv = hist[t];
            int v = hv;
#pragma unroll
            for (int off = 1; off < 64; off <<= 1) {
                int u2 = __shfl_down(v, off, 64);
                if (lane + off < 64) v += u2;
            }
            if (lane == 0) wsumi[wv] = v;   // wave total
            __syncthreads();
            int above = 0;
#pragma unroll
            for (int w2 = 1; w2 < 4; ++w2)
                if (wv + w2 < 4) above += wsumi[wv + w2];
            int cum = (v - hv) + above;
            if (cum < R && cum + hv >= R) {
                s_pref = pref | ((unsigned)t << sh);
                s_R = R - cum;
            }
            __syncthreads();
            pref = s_pref;
            R = s_R;
            __syncthreads();
        }
        tau = pref;
    }

    float m = fmaxf(mx, sink[h]);
    float part = 0.f;
    for (int l = t; l < ctx; l += 256) {
        unsigned k = keys[l];
        if (k >= tau) part += __expf(kval(k) - m);
    }
#pragma unroll
    for (int off = 32; off; off >>= 1) part += __shfl_xor(part, off, 64);
    __syncthreads();
    if (lane == 0) fred[wv] = part;
    __syncthreads();
    if (t == 0) {
        float denom = fred[0] + fred[1] + fred[2] + fred[3] + __expf(sink[h] - m);
        selm[nh] = m;
        seli[nh] = 1.0f / denom;
        selt[nh] = tau;
    }
}

// ============================================================
// MFMA weighted sum: grid (16 superchunks of 256 l, 64 n), 256 thr.
// 2 l-chunks accumulated in registers per block.
// ============================================================
__global__ __launch_bounds__(256) void attn_wsum_mfma(
    const float* __restrict__ logits, const float* __restrict__ kvc,
    const int* __restrict__ bt, const int* __restrict__ cl,
    const float* __restrict__ selm, const float* __restrict__ seli,
    const unsigned* __restrict__ selt, float* __restrict__ o)
{
    const int n = blockIdx.y, sbase = blockIdx.x * 256;
    const int ctx = cl[n];
    if (sbase >= ctx) return;

    __shared__ unsigned short ps[32 * 128];    // [h][l]
    __shared__ unsigned short kvt[192 * 128];  // [d][l]
    const int t = threadIdx.x;
    const int w = t >> 6, lane = t & 63;
    const int m16 = lane & 15, qd = lane >> 4;

    // per-head softmax params: h fixed per (t,i) -> load once
    float sm[2], sinv[2];
    unsigned stau[2];
#pragma unroll
    for (int i = 0; i < 2; ++i) {
        int nh = n * 32 + ((t + i * 256) >> 4);
        sm[i] = selm[nh];
        sinv[i] = seli[nh];
        stau[i] = selt[nh];
    }

    f32x4 acc[2][3];
#pragma unroll
    for (int mt = 0; mt < 2; ++mt)
#pragma unroll
        for (int nt = 0; nt < 3; ++nt) acc[mt][nt] = (f32x4){0.f, 0.f, 0.f, 0.f};

    for (int c = 0; c < 2; ++c) {
        const int base = sbase + c * 128;
        if (base >= ctx) break;
        const int vcount = min(128, ctx - base);

#pragma unroll
        for (int i = 0; i < 2; ++i) {
            int idx = t + i * 256;
            int hh = idx >> 4, u = idx & 15;
            int nh = n * 32 + hh;
            const float* lp = logits + ((long)nh << 12) + base + u * 8;
            float4 v0 = *(const float4*)lp, v1 = *(const float4*)(lp + 4);
            float vv[8] = {v0.x, v0.y, v0.z, v0.w, v1.x, v1.y, v1.z, v1.w};
            bf16x8 s;
#pragma unroll
            for (int j = 0; j < 8; ++j) {
                int ll = u * 8 + j;
                float p = 0.f;
                if (ll < vcount && fkey(vv[j]) >= stau[i]) p = __expf(vv[j] - sm[i]) * sinv[i];
                s[j] = (short)f2bf(p);
            }
            *(bf16x8*)(ps + hh * 128 + (u ^ (hh & 7)) * 8) = s;
        }
#pragma unroll
        for (int i = 0; i < 24; ++i) {
            int f = t + i * 256;
            int l = f & 127, d4 = f >> 7;
            int gl = min(base + l, ctx - 1);
            int slot = bt[n * 64 + (gl >> 6)] * 64 + (gl & 63);
            float4 v = *(const float4*)(kvc + (long)slot * 192 + d4 * 4);
            float vv[4] = {v.x, v.y, v.z, v.w};
#pragma unroll
            for (int e = 0; e < 4; ++e) {
                int d = d4 * 4 + e;
                int scol = (l & 7) | ((((l >> 3) ^ (d & 7)) & 15) << 3);
                kvt[d * 128 + scol] = f2bf(vv[e]);
            }
        }
        __syncthreads();

#pragma unroll
        for (int ks = 0; ks < 4; ++ks) {
            int u = ks * 4 + qd;
            bf16x8 a[2], b[3];
#pragma unroll
            for (int mt = 0; mt < 2; ++mt) {
                int row = mt * 16 + m16;
                a[mt] = *(const bf16x8*)(ps + row * 128 + (u ^ (row & 7)) * 8);
            }
#pragma unroll
            for (int nt = 0; nt < 3; ++nt) {
                int row = (3 * w + nt) * 16 + m16;
                b[nt] = *(const bf16x8*)(kvt + row * 128 + (u ^ (row & 7)) * 8);
            }
#pragma unroll
            for (int mt = 0; mt < 2; ++mt)
#pragma unroll
                for (int nt = 0; nt < 3; ++nt)
                    acc[mt][nt] = __builtin_amdgcn_mfma_f32_16x16x32_bf16(a[mt], b[nt], acc[mt][nt], 0, 0, 0);
        }
        __syncthreads();   // LDS reuse in next chunk
    }

#pragma unroll
    for (int mt = 0; mt < 2; ++mt)
#pragma unroll
        for (int nt = 0; nt < 3; ++nt) {
            int d = (3 * w + nt) * 16 + m16;
#pragma unroll
            for (int r = 0; r < 4; ++r) {
                int h = mt * 16 + qd * 4 + r;
                atomicAdd(&o[(long)n * 6144 + h * 192 + d], acc[mt][nt][r]);
            }
        }
}

// ============================================================
// launch — 9 dispatches (was 14)
// ============================================================
extern "C" void kernel_launch(void* const* d_in, const int* in_sizes, int n_in,
                              void* d_out, int out_size, void* d_ws, size_t ws_size,
                              hipStream_t stream)
{
    const float* x    = (const float*)d_in[0];
    float*       kvc  = (float*)d_in[1];
    const int*   bt   = (const int*)d_in[2];
    const int*   cl   = (const int*)d_in[3];
    const int*   smap = (const int*)d_in[4];
    const float* wqa  = (const float*)d_in[5];
    const float* qnw  = (const float*)d_in[6];
    const float* wqb  = (const float*)d_in[7];
    const float* wkv  = (const float*)d_in[8];
    const float* kvnw = (const float*)d_in[9];
    const float* woa  = (const float*)d_in[10];
    const float* wob  = (const float*)d_in[11];
    const float* sink = (const float*)d_in[12];
    float* ws  = (float*)d_ws;
    float* out = (float*)d_out;

    const int BIG = 1 << 30;

    hipMemsetAsync(ws, 0, (size_t)ZERO_F * sizeof(float), stream);

    // [qlat | kvr] = x @ [wq_a ; wkv]^T   (64x1728, K=4096, split at 1536)
    gemm_mfma<64><<<dim3(27, 16, 1), 256, 0, stream>>>(
        x, wqa, ws + OFF_QK, 4096, 4096, 1728, 256, 0, 0, 0,
        wkv, 1536, nullptr, 0);
    // fused: RMS(qlat) + RMS/RoPE/scatter(kv)
    post_a<<<64, 256, 0, stream>>>(ws + OFF_QK, qnw, kvnw, cl, smap, kvc);
    // q = qlat @ wq_b^T   (64x6144, K=1536; X ld = 1728)
    gemm_mfma<128><<<dim3(48, 6, 1), 256, 0, stream>>>(
        ws + OFF_QK, wqb, ws + OFF_Q, 1536, 1728, 6144, 256, 0, 0, 0,
        nullptr, BIG, nullptr, 0);
    // attention logits (RoPE on q fused into staging)
    attn_logits_mfma<<<dim3(16, 64), 256, 0, stream>>>(ws + OFF_Q, kvc, bt, cl,
                                                       ws + OFF_LOG);
    select_topk<<<2048, 256, 0, stream>>>(ws + OFF_LOG, cl, sink,
                                          ws + OFF_SELM, ws + OFF_SELI,
                                          (unsigned*)(ws + OFF_SELT));
    attn_wsum_mfma<<<dim3(16, 64), 256, 0, stream>>>(ws + OFF_LOG, kvc, bt, cl,
                                                     ws + OFF_SELM, ws + OFF_SELI,
                                                     (unsigned*)(ws + OFF_SELT),
                                                     ws + OFF_O);
    // grouped wo_a: 8 batches, 64x512, K=768  (also zeroes `out` for wo_b)
    gemm_mfma<128><<<dim3(4, 3, 8), 256, 0, stream>>>(
        ws + OFF_O, woa, ws + OFF_LAT, 768, 6144, 4096, 256,
        768, 512L * 768, 512, nullptr, BIG, out, 64L * 4096);
    // out = lat @ wo_b^T  (64x4096, K=4096)
    gemm_mfma<128><<<dim3(32, 8, 1), 256, 0, stream>>>(
        ws + OFF_LAT, wob, out, 4096, 4096, 4096, 512, 0, 0, 0,
        nullptr, BIG, nullptr, 0);
}